// Round 4
// baseline (345.694 us; speedup 1.0000x reference)
//
#include <hip/hip_runtime.h>
#include <math.h>

#define NF 128

// ---------------- graph preprocessing ----------------

__global__ __launch_bounds__(256) void count_kernel(const int* __restrict__ dst,
                                                    int* __restrict__ cnt, int E) {
  int e = blockIdx.x * 256 + threadIdx.x;
  if (e < E) atomicAdd(&cnt[dst[e]], 1);
}

__global__ __launch_bounds__(256) void dinv_kernel(const int* __restrict__ cnt,
                                                   float* __restrict__ dinv, int n) {
  int i = blockIdx.x * 256 + threadIdx.x;
  if (i < n) dinv[i] = rsqrtf((float)cnt[i] + 1.0f);  // +1 = self loop
}

__global__ __launch_bounds__(512) void chunk_sum(const int* __restrict__ cnt,
                                                 int* __restrict__ bsum, int n) {
  int i = blockIdx.x * 512 + threadIdx.x;
  int v = (i < n) ? cnt[i] : 0;
#pragma unroll
  for (int d = 1; d < 64; d <<= 1) v += __shfl_xor(v, d);
  __shared__ int ws[8];
  if ((threadIdx.x & 63) == 0) ws[threadIdx.x >> 6] = v;
  __syncthreads();
  if (threadIdx.x == 0) {
    int t = 0;
#pragma unroll
    for (int w = 0; w < 8; w++) t += ws[w];
    bsum[blockIdx.x] = t;
  }
}

__global__ void chunk_offsets(const int* __restrict__ bsum, int* __restrict__ boff,
                              int* __restrict__ rowptr, int nchunks, int n) {
  if (threadIdx.x == 0 && blockIdx.x == 0) {
    int run = 0;
    for (int b = 0; b < nchunks; b++) { boff[b] = run; run += bsum[b]; }
    rowptr[n] = run;
  }
}

__global__ __launch_bounds__(512) void chunk_scan(const int* __restrict__ cnt,
                                                  const int* __restrict__ boff,
                                                  int* __restrict__ rowptr,
                                                  int* __restrict__ cursor, int n) {
  int i = blockIdx.x * 512 + threadIdx.x;
  int lane = threadIdx.x & 63, wid = threadIdx.x >> 6;
  int v = (i < n) ? cnt[i] : 0;
  int incl = v;
#pragma unroll
  for (int d = 1; d < 64; d <<= 1) {
    int t = __shfl_up(incl, d);
    if (lane >= d) incl += t;
  }
  __shared__ int wt[8];
  if (lane == 63) wt[wid] = incl;
  __syncthreads();
  int woff = 0;
  for (int w = 0; w < wid; w++) woff += wt[w];
  int excl = boff[blockIdx.x] + woff + incl - v;
  if (i < n) { rowptr[i] = excl; cursor[i] = excl; }
}

__global__ __launch_bounds__(256) void scatter_kernel(const int* __restrict__ src,
                                                      const int* __restrict__ dst,
                                                      const float* __restrict__ dinv,
                                                      int* __restrict__ cursor,
                                                      int* __restrict__ csrc,
                                                      float* __restrict__ cw, int E) {
  int e = blockIdx.x * 256 + threadIdx.x;
  if (e < E) {
    int s = src[e], d = dst[e];
    int pos = atomicAdd(&cursor[d], 1);
    csrc[pos] = s;
    cw[pos] = dinv[s] * dinv[d];
  }
}

// ---------------- dense matmul: C[n][128] = A[n][128] @ W[128][128] ----------------
// block = 256 threads; 64 rows/block; thread micro-tile = 8 rows x 4 cols.
// LDS: sX 64x128 f32 (32KB) + sW 32x128 f32 chunk (16KB) = 48KB static.

__global__ __launch_bounds__(256) void mm128(const float* __restrict__ A,
                                             const float* __restrict__ W,
                                             float* __restrict__ C, int n) {
  __shared__ float sX[64 * NF];
  __shared__ float sW[32 * NF];
  int row0 = blockIdx.x * 64;

  for (int i = threadIdx.x; i < 64 * 32; i += 256) {   // 64 rows * 32 float4
    int r = i >> 5, c = i & 31;
    int row = row0 + r;
    float4 v = make_float4(0.f, 0.f, 0.f, 0.f);
    if (row < n) v = ((const float4*)(A + (size_t)row * NF))[c];
    ((float4*)(sX + r * NF))[c] = v;
  }

  int lane = threadIdx.x & 31;   // col group: cols 4*lane..4*lane+3
  int g = threadIdx.x >> 5;      // row group: rows g*8..g*8+7
  float4 acc[8];
#pragma unroll
  for (int r = 0; r < 8; r++) acc[r] = make_float4(0.f, 0.f, 0.f, 0.f);

  for (int kc = 0; kc < 4; kc++) {
    __syncthreads();
    for (int i = threadIdx.x; i < 32 * 32; i += 256)   // 32 k-rows * 32 float4
      ((float4*)sW)[i] = ((const float4*)(W + (size_t)kc * 32 * NF))[i];
    __syncthreads();

#pragma unroll
    for (int k = 0; k < 32; k += 4) {
      float4 xv[8];
#pragma unroll
      for (int r = 0; r < 8; r++)
        xv[r] = *(const float4*)(sX + (g * 8 + r) * NF + kc * 32 + k);
#pragma unroll
      for (int kk = 0; kk < 4; kk++) {
        float4 w = ((const float4*)(sW + (k + kk) * NF))[lane];
#pragma unroll
        for (int r = 0; r < 8; r++) {
          float f = (&xv[r].x)[kk];
          acc[r].x = fmaf(f, w.x, acc[r].x);
          acc[r].y = fmaf(f, w.y, acc[r].y);
          acc[r].z = fmaf(f, w.z, acc[r].z);
          acc[r].w = fmaf(f, w.w, acc[r].w);
        }
      }
    }
  }

#pragma unroll
  for (int r = 0; r < 8; r++) {
    int row = row0 + g * 8 + r;
    if (row < n) ((float4*)(C + (size_t)row * NF))[lane] = acc[r];
  }
}

// ---------------- aggregation: out[i] = relu( sum_e w_e*T[src_e] + dinv^2*T[i] + b ) ----
// one wave (64 lanes) per node; lane owns 2 features (float2).

__global__ __launch_bounds__(256) void aggregate(const float* __restrict__ T,
                                                 const int* __restrict__ rowptr,
                                                 const int* __restrict__ csrc,
                                                 const float* __restrict__ cw,
                                                 const float* __restrict__ dinv,
                                                 const float* __restrict__ bias,
                                                 float* __restrict__ out, int n,
                                                 int do_relu) {
  int wid = threadIdx.x >> 6;
  int lane = threadIdx.x & 63;
  int i = blockIdx.x * 4 + wid;
  if (i >= n) return;

  float di = dinv[i];
  float self_w = di * di;
  float2 acc = ((const float2*)(T + (size_t)i * NF))[lane];
  acc.x *= self_w;
  acc.y *= self_w;

  int beg = rowptr[i], end = rowptr[i + 1];
  int e = beg;
  int sN = 0; float wN = 0.f;
  if (e < end) { sN = csrc[e]; wN = cw[e]; }
  while (e < end) {
    int s = sN; float w = wN;
    if (e + 1 < end) { sN = csrc[e + 1]; wN = cw[e + 1]; }
    float2 v = ((const float2*)(T + (size_t)s * NF))[lane];
    acc.x = fmaf(w, v.x, acc.x);
    acc.y = fmaf(w, v.y, acc.y);
    ++e;
  }

  float2 b = ((const float2*)bias)[lane];
  acc.x += b.x;
  acc.y += b.y;
  if (do_relu) {
    acc.x = fmaxf(acc.x, 0.f);
    acc.y = fmaxf(acc.y, 0.f);
  }
  ((float2*)(out + (size_t)i * NF))[lane] = acc;
}

// ---------------- head: out[i] = softmax(A[i] @ Wout + bout), C=5 ----------------

__global__ __launch_bounds__(256) void head(const float* __restrict__ A,
                                            const float* __restrict__ Wout,
                                            const float* __restrict__ bout,
                                            float* __restrict__ out, int n) {
  int wid = threadIdx.x >> 6;
  int lane = threadIdx.x & 63;
  int i = blockIdx.x * 4 + wid;
  if (i >= n) return;

  float2 a = ((const float2*)(A + (size_t)i * NF))[lane];
  float p[5];
#pragma unroll
  for (int c = 0; c < 5; c++)
    p[c] = fmaf(a.x, Wout[(2 * lane) * 5 + c], a.y * Wout[(2 * lane + 1) * 5 + c]);

#pragma unroll
  for (int d = 1; d < 64; d <<= 1) {
#pragma unroll
    for (int c = 0; c < 5; c++) p[c] += __shfl_xor(p[c], d);
  }

#pragma unroll
  for (int c = 0; c < 5; c++) p[c] += bout[c];

  float m = p[0];
#pragma unroll
  for (int c = 1; c < 5; c++) m = fmaxf(m, p[c]);
  float s = 0.f;
  float ex[5];
#pragma unroll
  for (int c = 0; c < 5; c++) { ex[c] = expf(p[c] - m); s += ex[c]; }
  float inv = 1.0f / s;
  if (lane < 5) out[(size_t)i * 5 + lane] = ex[lane] * inv;
}

// ---------------- launch ----------------

extern "C" void kernel_launch(void* const* d_in, const int* in_sizes, int n_in,
                              void* d_out, int out_size, void* d_ws, size_t ws_size,
                              hipStream_t stream) {
  const float* x    = (const float*)d_in[0];
  const int*   ei   = (const int*)d_in[1];
  const float* W1   = (const float*)d_in[2];
  const float* b1   = (const float*)d_in[3];
  const float* W2   = (const float*)d_in[4];
  const float* b2   = (const float*)d_in[5];
  const float* Wout = (const float*)d_in[6];
  const float* bout = (const float*)d_in[7];
  float* out = (float*)d_out;

  int n = in_sizes[0] / NF;   // 50000
  int E = in_sizes[1] / 2;    // 600000
  const int* esrc = ei;
  const int* edst = ei + E;

  char* p = (char*)d_ws;
  auto alloc = [&](size_t bytes) -> char* {
    char* r = p;
    p += (bytes + 255) & ~(size_t)255;
    return r;
  };
  int nchunks = (n + 511) / 512;
  int*   cnt    = (int*)alloc((size_t)n * 4);
  int*   rowptr = (int*)alloc((size_t)(n + 1) * 4);
  int*   cursor = (int*)alloc((size_t)n * 4);
  int*   bsum   = (int*)alloc((size_t)nchunks * 4);
  int*   boff   = (int*)alloc((size_t)nchunks * 4);
  int*   csrc   = (int*)alloc((size_t)E * 4);
  float* cw     = (float*)alloc((size_t)E * 4);
  float* dinv   = (float*)alloc((size_t)n * 4);
  float* T      = (float*)alloc((size_t)n * NF * 4);
  float* Abuf   = (float*)alloc((size_t)n * NF * 4);

  hipMemsetAsync(cnt, 0, (size_t)n * 4, stream);
  count_kernel<<<(E + 255) / 256, 256, 0, stream>>>(edst, cnt, E);
  dinv_kernel<<<(n + 255) / 256, 256, 0, stream>>>(cnt, dinv, n);
  chunk_sum<<<nchunks, 512, 0, stream>>>(cnt, bsum, n);
  chunk_offsets<<<1, 64, 0, stream>>>(bsum, boff, rowptr, nchunks, n);
  chunk_scan<<<nchunks, 512, 0, stream>>>(cnt, boff, rowptr, cursor, n);
  scatter_kernel<<<(E + 255) / 256, 256, 0, stream>>>(esrc, edst, dinv, cursor, csrc, cw, E);

  // layer 1: T = x @ W1 ; Abuf = relu(agg(T) + b1)
  mm128<<<(n + 63) / 64, 256, 0, stream>>>(x, W1, T, n);
  aggregate<<<(n + 3) / 4, 256, 0, stream>>>(T, rowptr, csrc, cw, dinv, b1, Abuf, n, 1);
  // layer 2: T = Abuf @ W2 ; Abuf = relu(agg(T) + b2)
  mm128<<<(n + 63) / 64, 256, 0, stream>>>(Abuf, W2, T, n);
  aggregate<<<(n + 3) / 4, 256, 0, stream>>>(T, rowptr, csrc, cw, dinv, b2, Abuf, n, 1);
  // head
  head<<<(n + 3) / 4, 256, 0, stream>>>(Abuf, Wout, bout, out, n);
}

// Round 7
// 316.128 us; speedup vs baseline: 1.0935x; 1.0935x over previous
//
#include <hip/hip_runtime.h>
#include <math.h>

#define NF 128

// ---------------- graph preprocessing ----------------

__global__ __launch_bounds__(256) void count_kernel(const int* __restrict__ dst,
                                                    int* __restrict__ cnt, int E) {
  int e = blockIdx.x * 256 + threadIdx.x;
  if (e < E) atomicAdd(&cnt[dst[e]], 1);
}

__global__ __launch_bounds__(256) void dinv_kernel(const int* __restrict__ cnt,
                                                   float* __restrict__ dinv, int n) {
  int i = blockIdx.x * 256 + threadIdx.x;
  if (i < n) dinv[i] = rsqrtf((float)cnt[i] + 1.0f);  // +1 = self loop
}

__global__ __launch_bounds__(512) void chunk_sum(const int* __restrict__ cnt,
                                                 int* __restrict__ bsum, int n) {
  int i = blockIdx.x * 512 + threadIdx.x;
  int v = (i < n) ? cnt[i] : 0;
#pragma unroll
  for (int d = 1; d < 64; d <<= 1) v += __shfl_xor(v, d);
  __shared__ int ws[8];
  if ((threadIdx.x & 63) == 0) ws[threadIdx.x >> 6] = v;
  __syncthreads();
  if (threadIdx.x == 0) {
    int t = 0;
#pragma unroll
    for (int w = 0; w < 8; w++) t += ws[w];
    bsum[blockIdx.x] = t;
  }
}

// parallel exclusive scan of bsum[0..nchunks) — one block, nchunks <= 1024
__global__ __launch_bounds__(1024) void chunk_offsets_par(const int* __restrict__ bsum,
                                                          int* __restrict__ boff,
                                                          int* __restrict__ rowptr,
                                                          int nchunks, int n) {
  int t = threadIdx.x, lane = t & 63, w = t >> 6;
  int v = (t < nchunks) ? bsum[t] : 0;
  int incl = v;
#pragma unroll
  for (int d = 1; d < 64; d <<= 1) {
    int tmp = __shfl_up(incl, d);
    if (lane >= d) incl += tmp;
  }
  __shared__ int wt[16];
  if (lane == 63) wt[w] = incl;
  __syncthreads();
  int woff = 0;
  for (int k = 0; k < w; ++k) woff += wt[k];
  int excl = woff + incl - v;
  if (t < nchunks) boff[t] = excl;
  if (t == nchunks - 1) rowptr[n] = excl + v;
}

__global__ __launch_bounds__(512) void chunk_scan(const int* __restrict__ cnt,
                                                  const int* __restrict__ boff,
                                                  int* __restrict__ rowptr,
                                                  int* __restrict__ cursor, int n) {
  int i = blockIdx.x * 512 + threadIdx.x;
  int lane = threadIdx.x & 63, wid = threadIdx.x >> 6;
  int v = (i < n) ? cnt[i] : 0;
  int incl = v;
#pragma unroll
  for (int d = 1; d < 64; d <<= 1) {
    int t = __shfl_up(incl, d);
    if (lane >= d) incl += t;
  }
  __shared__ int wt[8];
  if (lane == 63) wt[wid] = incl;
  __syncthreads();
  int woff = 0;
  for (int w = 0; w < wid; w++) woff += wt[w];
  int excl = boff[blockIdx.x] + woff + incl - v;
  if (i < n) { rowptr[i] = excl; cursor[i] = excl; }
}

// scatter only the source index; weights are folded into T (dinv-scaled rows)
__global__ __launch_bounds__(256) void scatter_kernel(const int* __restrict__ src,
                                                      const int* __restrict__ dst,
                                                      int* __restrict__ cursor,
                                                      int* __restrict__ csrc, int E) {
  int e = blockIdx.x * 256 + threadIdx.x;
  if (e < E) {
    int s = src[e], d = dst[e];
    int pos = atomicAdd(&cursor[d], 1);
    csrc[pos] = s;
  }
}

// ---------------- dense matmul: C[n][128] = dinv[row] * (A[n][128] @ W[128][128]) ----
// block = 256 threads; 64 rows/block; thread micro-tile = 8 rows x 4 cols.

__global__ __launch_bounds__(256) void mm128(const float* __restrict__ A,
                                             const float* __restrict__ W,
                                             const float* __restrict__ dinv,
                                             float* __restrict__ C, int n) {
  __shared__ float sX[64 * NF];
  __shared__ float sW[32 * NF];
  int row0 = blockIdx.x * 64;

  for (int i = threadIdx.x; i < 64 * 32; i += 256) {   // 64 rows * 32 float4
    int r = i >> 5, c = i & 31;
    int row = row0 + r;
    float4 v = make_float4(0.f, 0.f, 0.f, 0.f);
    if (row < n) v = ((const float4*)(A + (size_t)row * NF))[c];
    ((float4*)(sX + r * NF))[c] = v;
  }

  int lane = threadIdx.x & 31;   // col group: cols 4*lane..4*lane+3
  int g = threadIdx.x >> 5;      // row group: rows g*8..g*8+7
  float4 acc[8];
#pragma unroll
  for (int r = 0; r < 8; r++) acc[r] = make_float4(0.f, 0.f, 0.f, 0.f);

  for (int kc = 0; kc < 4; kc++) {
    __syncthreads();
    for (int i = threadIdx.x; i < 32 * 32; i += 256)   // 32 k-rows * 32 float4
      ((float4*)sW)[i] = ((const float4*)(W + (size_t)kc * 32 * NF))[i];
    __syncthreads();

#pragma unroll
    for (int k = 0; k < 32; k += 4) {
      float4 xv[8];
#pragma unroll
      for (int r = 0; r < 8; r++)
        xv[r] = *(const float4*)(sX + (g * 8 + r) * NF + kc * 32 + k);
#pragma unroll
      for (int kk = 0; kk < 4; kk++) {
        float4 w = ((const float4*)(sW + (k + kk) * NF))[lane];
#pragma unroll
        for (int r = 0; r < 8; r++) {
          float f = (&xv[r].x)[kk];
          acc[r].x = fmaf(f, w.x, acc[r].x);
          acc[r].y = fmaf(f, w.y, acc[r].y);
          acc[r].z = fmaf(f, w.z, acc[r].z);
          acc[r].w = fmaf(f, w.w, acc[r].w);
        }
      }
    }
  }

#pragma unroll
  for (int r = 0; r < 8; r++) {
    int row = row0 + g * 8 + r;
    if (row < n) {
      float di = dinv[row];
      acc[r].x *= di; acc[r].y *= di; acc[r].z *= di; acc[r].w *= di;
      ((float4*)(C + (size_t)row * NF))[lane] = acc[r];
    }
  }
}

// ---------------- aggregation ----------------
// T rows are pre-scaled by dinv[src].  out_row(i) = relu( dinv[i]*(T[i] + sum_e T[src_e]) + b )
// MODE 0: write full 128-f row to out.  MODE 1: fused head — logits@Wout, softmax, write 5 floats.
// One wave per node; lane owns features (2*lane, 2*lane+1).  4-way ILP on the gather chain.

template <int MODE>
__device__ __forceinline__ void aggregate_body(const float* __restrict__ T,
                                               const int* __restrict__ rowptr,
                                               const int* __restrict__ csrc,
                                               const float* __restrict__ dinv,
                                               const float* __restrict__ bias,
                                               const float* __restrict__ Wout,
                                               const float* __restrict__ bout,
                                               float* __restrict__ out, int n) {
  int wid = threadIdx.x >> 6;
  int lane = threadIdx.x & 63;
  int i = blockIdx.x * 4 + wid;
  if (i >= n) return;

  float2 a0 = ((const float2*)(T + (size_t)i * NF))[lane];  // self (already dinv[i]-scaled)
  float2 a1 = make_float2(0.f, 0.f);
  float2 a2 = make_float2(0.f, 0.f);
  float2 a3 = make_float2(0.f, 0.f);

  int beg = rowptr[i], end = rowptr[i + 1];
  int e = beg;
  for (; e + 4 <= end; e += 4) {
    int s0 = csrc[e + 0], s1 = csrc[e + 1], s2 = csrc[e + 2], s3 = csrc[e + 3];
    float2 v0 = ((const float2*)(T + (size_t)s0 * NF))[lane];
    float2 v1 = ((const float2*)(T + (size_t)s1 * NF))[lane];
    float2 v2 = ((const float2*)(T + (size_t)s2 * NF))[lane];
    float2 v3 = ((const float2*)(T + (size_t)s3 * NF))[lane];
    a0.x += v0.x; a0.y += v0.y;
    a1.x += v1.x; a1.y += v1.y;
    a2.x += v2.x; a2.y += v2.y;
    a3.x += v3.x; a3.y += v3.y;
  }
  for (; e < end; ++e) {
    int s = csrc[e];
    float2 v = ((const float2*)(T + (size_t)s * NF))[lane];
    a0.x += v.x; a0.y += v.y;
  }

  float2 acc;
  acc.x = (a0.x + a1.x) + (a2.x + a3.x);
  acc.y = (a0.y + a1.y) + (a2.y + a3.y);

  float di = dinv[i];
  float2 b = ((const float2*)bias)[lane];
  acc.x = fmaxf(fmaf(di, acc.x, b.x), 0.f);
  acc.y = fmaxf(fmaf(di, acc.y, b.y), 0.f);

  if (MODE == 0) {
    ((float2*)(out + (size_t)i * NF))[lane] = acc;
  } else {
    // fused head: logits = row @ Wout + bout ; softmax ; write 5
    float p0, p1, p2, p3, p4;
    {
      const float* w0 = Wout + (2 * lane) * 5;
      const float* w1 = Wout + (2 * lane + 1) * 5;
      p0 = fmaf(acc.x, w0[0], acc.y * w1[0]);
      p1 = fmaf(acc.x, w0[1], acc.y * w1[1]);
      p2 = fmaf(acc.x, w0[2], acc.y * w1[2]);
      p3 = fmaf(acc.x, w0[3], acc.y * w1[3]);
      p4 = fmaf(acc.x, w0[4], acc.y * w1[4]);
    }
#pragma unroll
    for (int d = 1; d < 64; d <<= 1) {
      p0 += __shfl_xor(p0, d);
      p1 += __shfl_xor(p1, d);
      p2 += __shfl_xor(p2, d);
      p3 += __shfl_xor(p3, d);
      p4 += __shfl_xor(p4, d);
    }
    p0 += bout[0]; p1 += bout[1]; p2 += bout[2]; p3 += bout[3]; p4 += bout[4];
    float m = fmaxf(fmaxf(fmaxf(p0, p1), fmaxf(p2, p3)), p4);
    float e0 = expf(p0 - m), e1 = expf(p1 - m), e2 = expf(p2 - m),
          e3 = expf(p3 - m), e4 = expf(p4 - m);
    float inv = 1.0f / (e0 + e1 + e2 + e3 + e4);
    float val = (lane == 0) ? e0 : (lane == 1) ? e1 : (lane == 2) ? e2
              : (lane == 3) ? e3 : e4;
    if (lane < 5) out[(size_t)i * 5 + lane] = val * inv;
  }
}

__global__ __launch_bounds__(256) void aggregate_row(const float* __restrict__ T,
                                                     const int* __restrict__ rowptr,
                                                     const int* __restrict__ csrc,
                                                     const float* __restrict__ dinv,
                                                     const float* __restrict__ bias,
                                                     float* __restrict__ out, int n) {
  aggregate_body<0>(T, rowptr, csrc, dinv, bias, nullptr, nullptr, out, n);
}

__global__ __launch_bounds__(256) void aggregate_head(const float* __restrict__ T,
                                                      const int* __restrict__ rowptr,
                                                      const int* __restrict__ csrc,
                                                      const float* __restrict__ dinv,
                                                      const float* __restrict__ bias,
                                                      const float* __restrict__ Wout,
                                                      const float* __restrict__ bout,
                                                      float* __restrict__ out, int n) {
  aggregate_body<1>(T, rowptr, csrc, dinv, bias, Wout, bout, out, n);
}

// ---------------- launch ----------------

extern "C" void kernel_launch(void* const* d_in, const int* in_sizes, int n_in,
                              void* d_out, int out_size, void* d_ws, size_t ws_size,
                              hipStream_t stream) {
  const float* x    = (const float*)d_in[0];
  const int*   ei   = (const int*)d_in[1];
  const float* W1   = (const float*)d_in[2];
  const float* b1   = (const float*)d_in[3];
  const float* W2   = (const float*)d_in[4];
  const float* b2   = (const float*)d_in[5];
  const float* Wout = (const float*)d_in[6];
  const float* bout = (const float*)d_in[7];
  float* out = (float*)d_out;

  int n = in_sizes[0] / NF;   // 50000
  int E = in_sizes[1] / 2;    // 600000
  const int* esrc = ei;
  const int* edst = ei + E;

  char* p = (char*)d_ws;
  auto alloc = [&](size_t bytes) -> char* {
    char* r = p;
    p += (bytes + 255) & ~(size_t)255;
    return r;
  };
  int nchunks = (n + 511) / 512;
  int*   cnt    = (int*)alloc((size_t)n * 4);
  int*   rowptr = (int*)alloc((size_t)(n + 1) * 4);
  int*   cursor = (int*)alloc((size_t)n * 4);
  int*   bsum   = (int*)alloc((size_t)nchunks * 4);
  int*   boff   = (int*)alloc((size_t)nchunks * 4);
  int*   csrc   = (int*)alloc((size_t)E * 4);
  float* dinv   = (float*)alloc((size_t)n * 4);
  float* T      = (float*)alloc((size_t)n * NF * 4);
  float* Abuf   = (float*)alloc((size_t)n * NF * 4);

  hipMemsetAsync(cnt, 0, (size_t)n * 4, stream);
  count_kernel<<<(E + 255) / 256, 256, 0, stream>>>(edst, cnt, E);
  dinv_kernel<<<(n + 255) / 256, 256, 0, stream>>>(cnt, dinv, n);
  chunk_sum<<<nchunks, 512, 0, stream>>>(cnt, bsum, n);
  chunk_offsets_par<<<1, 1024, 0, stream>>>(bsum, boff, rowptr, nchunks, n);
  chunk_scan<<<nchunks, 512, 0, stream>>>(cnt, boff, rowptr, cursor, n);
  scatter_kernel<<<(E + 255) / 256, 256, 0, stream>>>(esrc, edst, cursor, csrc, E);

  // layer 1: T = dinv * (x @ W1) ; Abuf = relu(dinv*(sum T) + b1)
  mm128<<<(n + 63) / 64, 256, 0, stream>>>(x, W1, dinv, T, n);
  aggregate_row<<<(n + 3) / 4, 256, 0, stream>>>(T, rowptr, csrc, dinv, b1, Abuf, n);
  // layer 2: T = dinv * (Abuf @ W2) ; out = softmax(relu(dinv*(sum T) + b2) @ Wout + bout)
  mm128<<<(n + 63) / 64, 256, 0, stream>>>(Abuf, W2, dinv, T, n);
  aggregate_head<<<(n + 3) / 4, 256, 0, stream>>>(T, rowptr, csrc, dinv, b2, Wout, bout, out, n);
}